// Round 3
// baseline (486.991 us; speedup 1.0000x reference)
//
#include <hip/hip_runtime.h>

// MegalodonEMA via chunked state-space form, chunk C = 64 = wave width.
// Per (d): tables T2[r][n] = c_n * w_n^r (r=0..64), K[p] = sum_n c_n w_n^p.
// Per chunk, lane j:
//   y[l0+j] = sum_n T2[j+1][n]*h_n  +  sum_{m<=j} K[j-m]*x[l0+m]
//   h_n    <- w_n^64 * h_n + sum_m w_n^{63-m} x[l0+m]   (Horner, lane n)
// Cross-lane broadcasts (h_n, x[m]) via v_readlane (imm lane, SGPR operand).
// Block = one d (4 waves x 2 batch cols); main loop has ZERO barriers.

#define L_SEQ 2048
#define BSZ 8
#define DIM 1024
#define NDIM 64
#define CHUNK 64
#define NCHUNK 32
#define BD 8192
#define TP 68   // T2 row pitch (words): bank = (4(r+q)+e)%32 -> 8-way quad
                // spread on b128 = bandwidth floor; quad index stays uniform
                // across lanes so readlane h-indices are immediates.

__device__ __forceinline__ float rl(float v, int lane) {
    return __int_as_float(__builtin_amdgcn_readlane(__float_as_int(v), lane));
}

__global__ __launch_bounds__(256, 4) void mega_ema_kernel(
    const float* __restrict__ x,
    const float* __restrict__ damping_factor,
    const float* __restrict__ decay_factor,
    const float* __restrict__ ema_mat,
    const float* __restrict__ proj,
    const float* __restrict__ rw,
    float* __restrict__ out)
{
    __shared__ float T2[65 * TP];
    __shared__ float Kt[128];   // Kt[64+p] = K[p], Kt[0..63] = 0 (causal pad)

    const int d    = blockIdx.x;
    const int tid  = threadIdx.x;
    const int lane = tid & 63;
    const int wv   = tid >> 6;   // 0..3

    // ---- per-(d,n) mode params (lane = n) ----
    const int pidx = d * NDIM + lane;
    const float sd = 1.0f / (1.0f + __expf(-damping_factor[pidx]));
    const float sc = 1.0f / (1.0f + __expf(-decay_factor[pidx]));
    const float w  = 1.0f - sd * sc;                       // in (0,1)
    const float c  = sd * ema_mat[pidx] * proj[pidx] * 0.125f; // /sqrt(64)
    const float lw = log2f(w);
    const float w64 = exp2f(64.0f * lw);

    // ---- build T2 table: rows r = wv, wv+4, ... <= 64 ----
    for (int r = wv; r <= 64; r += 4) {
        T2[r * TP + lane] = c * exp2f((float)r * lw);
    }
    __syncthreads();
    // ---- build K from T2 column sums (wave 1; staggered n to spread banks) ----
    if (tid < 64) {
        Kt[tid] = 0.0f;
    } else if (tid < 128) {
        const int p = tid - 64;
        float s = 0.0f;
        for (int i = 0; i < 64; ++i) {
            const int n = (i + p) & 63;
            s += T2[p * TP + n];
        }
        Kt[64 + p] = s;
    }
    __syncthreads();
    // ---- main loop: no barriers (tables read-only, x/h in registers) ----

    const int b0 = wv * 2;
    const float* xc0 = x + (size_t)b0 * DIM + d;
    const float* xc1 = xc0 + DIM;
    float* oc0 = out + (size_t)b0 * DIM + d;
    float* oc1 = oc0 + DIM;
    const float rwd = rw[d];

    const float* trow = &T2[(lane + 1) * TP]; // row j+1; 272B*(j+1): 16B aligned
    const float* kb   = &Kt[lane];            // kb[64-m] = K[j-m] (>=1: in range)

    float h0 = 0.0f, h1 = 0.0f;
    float x0 = xc0[(size_t)lane * BD];
    float x1 = xc1[(size_t)lane * BD];

    for (int g = 0; g < NCHUNK; ++g) {
        // prefetch next chunk's x (register double-buffer; hides HBM latency)
        float nx0 = 0.0f, nx1 = 0.0f;
        if (g + 1 < NCHUNK) {
            const size_t off = (size_t)((g + 1) * CHUNK + lane) * BD;
            nx0 = xc0[off];
            nx1 = xc1[off];
        }

        // carry term: A[j] = sum_n T2[j+1][n] * h_n   (16 x ds_read_b128)
        float A0 = 0.0f, A1 = 0.0f;
        #pragma unroll
        for (int q = 0; q < 16; ++q) {
            const float4 tv = *(const float4*)(trow + q * 4);
            A0 = fmaf(tv.x, rl(h0, 4*q+0), A0);
            A1 = fmaf(tv.x, rl(h1, 4*q+0), A1);
            A0 = fmaf(tv.y, rl(h0, 4*q+1), A0);
            A1 = fmaf(tv.y, rl(h1, 4*q+1), A1);
            A0 = fmaf(tv.z, rl(h0, 4*q+2), A0);
            A1 = fmaf(tv.z, rl(h1, 4*q+2), A1);
            A0 = fmaf(tv.w, rl(h0, 4*q+3), A0);
            A1 = fmaf(tv.w, rl(h1, 4*q+3), A1);
        }

        // Toeplitz (intra-chunk causal conv) fused with state scan
        float t0 = 0.0f, t1 = 0.0f, s0 = 0.0f, s1 = 0.0f;
        #pragma unroll
        for (int m = 0; m < CHUNK; ++m) {
            const float xm0 = rl(x0, m);
            const float xm1 = rl(x1, m);
            s0 = fmaf(w, s0, xm0);          // Horner: sum w^{63-m} x[m]
            s1 = fmaf(w, s1, xm1);
            const float kv = kb[64 - m];    // K[j-m], 0 for m>j
            t0 = fmaf(kv, xm0, t0);
            t1 = fmaf(kv, xm1, t1);
        }

        // state carry across chunks
        h0 = fmaf(w64, h0, s0);
        h1 = fmaf(w64, h1, s1);

        // residual + silu + store
        const float v0 = A0 + t0 + x0 * rwd;
        const float v1 = A1 + t1 + x1 * rwd;
        const float r0 = v0 / (1.0f + __expf(-v0));
        const float r1 = v1 / (1.0f + __expf(-v1));
        const size_t ooff = (size_t)(g * CHUNK + lane) * BD;
        oc0[ooff] = r0;
        oc1[ooff] = r1;

        x0 = nx0;
        x1 = nx1;
    }
}

extern "C" void kernel_launch(void* const* d_in, const int* in_sizes, int n_in,
                              void* d_out, int out_size, void* d_ws, size_t ws_size,
                              hipStream_t stream) {
    const float* x   = (const float*)d_in[0];
    const float* df  = (const float*)d_in[1];
    const float* cf  = (const float*)d_in[2];
    const float* em  = (const float*)d_in[3];
    const float* pj  = (const float*)d_in[4];
    const float* rw  = (const float*)d_in[5];
    float* out = (float*)d_out;

    dim3 grid(DIM);    // one block per d
    dim3 block(256);   // 4 waves x 2 batch columns
    mega_ema_kernel<<<grid, block, 0, stream>>>(x, df, cf, em, pj, rw, out);
}

// Round 4
// 308.331 us; speedup vs baseline: 1.5794x; 1.5794x over previous
//
#include <hip/hip_runtime.h>

// MegalodonEMA single-pass: 64-mode recurrence, coalesced via LDS transpose.
// Block = (b, 16 consecutive d), 128 threads = 2 waves.
// Lane role: col = wv*8 + (lane>>3)  (16 cols/block), q = lane&7 = mode-group.
// Each lane: 8 modes n = q*8+i. Per timestep: 16 FMA + 3 shfl_xor butterfly.
// Deferred silu: lane keeps v for timesteps t%8==q, silu once per 8 steps.
// x staged per 64-step chunk into LDS (float4, reg double-buffered);
// y staged in LDS tile, stored coalesced. 2 barriers per chunk.

#define LSEQ 2048
#define BSZ 8
#define DIM 1024
#define ND 64
#define CH 64
#define NCH 32
#define TD 16
#define BD 8192
#define YP 20   // ytile pitch: bank (20q + c)%32 -> worst 2-way (free)

__global__ __launch_bounds__(128) void mega_kernel(
    const float* __restrict__ x,
    const float* __restrict__ dfp,
    const float* __restrict__ cfp,
    const float* __restrict__ emp,
    const float* __restrict__ pjp,
    const float* __restrict__ rwp,
    float* __restrict__ out)
{
    __shared__ float xb[2][CH * TD];  // 2 x 4KB
    __shared__ float yt[CH * YP];     // 5KB

    const int tid  = threadIdx.x;
    const int lane = tid & 63;
    const int wv   = tid >> 6;
    const int q    = lane & 7;        // mode-group
    const int csub = lane >> 3;       // 0..7
    const int col  = wv * 8 + csub;   // 0..15
    const int blk  = blockIdx.x;
    const int b    = blk >> 6;        // 0..7
    const int d0   = (blk & 63) * TD;
    const int d    = d0 + col;

    // ---- per-lane mode params: n = q*8 + i ----
    float w[8], cc[8];
    {
        const int pb = d * ND + q * 8;
        const float4 df0 = *(const float4*)(dfp + pb);
        const float4 df1 = *(const float4*)(dfp + pb + 4);
        const float4 cf0 = *(const float4*)(cfp + pb);
        const float4 cf1 = *(const float4*)(cfp + pb + 4);
        const float4 em0 = *(const float4*)(emp + pb);
        const float4 em1 = *(const float4*)(emp + pb + 4);
        const float4 pj0 = *(const float4*)(pjp + pb);
        const float4 pj1 = *(const float4*)(pjp + pb + 4);
        const float dfv[8] = {df0.x, df0.y, df0.z, df0.w, df1.x, df1.y, df1.z, df1.w};
        const float cfv[8] = {cf0.x, cf0.y, cf0.z, cf0.w, cf1.x, cf1.y, cf1.z, cf1.w};
        const float emv[8] = {em0.x, em0.y, em0.z, em0.w, em1.x, em1.y, em1.z, em1.w};
        const float pjv[8] = {pj0.x, pj0.y, pj0.z, pj0.w, pj1.x, pj1.y, pj1.z, pj1.w};
        #pragma unroll
        for (int i = 0; i < 8; ++i) {
            const float sd = 1.0f / (1.0f + __expf(-dfv[i]));
            const float sc = 1.0f / (1.0f + __expf(-cfv[i]));
            w[i]  = 1.0f - sd * sc;
            cc[i] = sd * emv[i] * pjv[i] * 0.125f;  // 1/sqrt(64)
        }
    }
    const float rwd = rwp[d];

    const float* xg = x   + (size_t)b * DIM + d0;
    float*       og = out + (size_t)b * DIM + d0;

    // staging map: f in {tid, tid+128}: row r=f>>2, col4 c4=(f&3)*4
    const int r0 = tid >> 2;
    const int c4 = (tid & 3) * 4;

    float4 nx0 = *(const float4*)(xg + (size_t)r0 * BD + c4);
    float4 nx1 = *(const float4*)(xg + (size_t)(r0 + 32) * BD + c4);

    float h[8];
    #pragma unroll
    for (int i = 0; i < 8; ++i) h[i] = 0.0f;

    for (int g = 0; g < NCH; ++g) {
        float* xbuf = xb[g & 1];
        *(float4*)(xbuf + r0 * TD + c4) = nx0;
        *(float4*)(xbuf + (r0 + 32) * TD + c4) = nx1;
        if (g + 1 < NCH) {  // prefetch next chunk (consumed next iter)
            nx0 = *(const float4*)(xg + (size_t)((g + 1) * CH + r0) * BD + c4);
            nx1 = *(const float4*)(xg + (size_t)((g + 1) * CH + r0 + 32) * BD + c4);
        }
        __syncthreads();  // x tile ready

        #pragma unroll 2
        for (int t8 = 0; t8 < 8; ++t8) {
            float vsave = 0.0f;
            #pragma unroll
            for (int k = 0; k < 8; ++k) {
                const float xv = xbuf[(t8 * 8 + k) * TD + col];  // 8-way bcast, 8 banks
                float a0 = 0.0f, a1 = 0.0f;  // split acc chain: 4-deep each
                #pragma unroll
                for (int i = 0; i < 4; ++i) {
                    h[i] = fmaf(w[i], h[i], xv);
                    a0 = fmaf(cc[i], h[i], a0);
                }
                #pragma unroll
                for (int i = 4; i < 8; ++i) {
                    h[i] = fmaf(w[i], h[i], xv);
                    a1 = fmaf(cc[i], h[i], a1);
                }
                float acc = a0 + a1;
                acc += __shfl_xor(acc, 1);
                acc += __shfl_xor(acc, 2);
                acc += __shfl_xor(acc, 4);   // all 8 mode-group lanes have y
                const float v = fmaf(rwd, xv, acc);
                if (q == k) vsave = v;       // compile-time k: cmp+cndmask
            }
            const float sv = vsave / (1.0f + __expf(-vsave));  // silu, 1/8 rate
            yt[(t8 * 8 + q) * YP + col] = sv;
        }
        __syncthreads();  // y tile complete (also: xbuf reads done)

        const float4 o0 = *(const float4*)(yt + r0 * YP + c4);
        const float4 o1 = *(const float4*)(yt + (r0 + 32) * YP + c4);
        *(float4*)(og + (size_t)(g * CH + r0) * BD + c4) = o0;
        *(float4*)(og + (size_t)(g * CH + r0 + 32) * BD + c4) = o1;
        // no third barrier: next yt write is after next __syncthreads,
        // which orders these ds_reads; next ds_write targets xb[(g+1)&1],
        // whose readers finished two barriers ago.
    }
}

extern "C" void kernel_launch(void* const* d_in, const int* in_sizes, int n_in,
                              void* d_out, int out_size, void* d_ws, size_t ws_size,
                              hipStream_t stream) {
    const float* x  = (const float*)d_in[0];
    const float* df = (const float*)d_in[1];
    const float* cf = (const float*)d_in[2];
    const float* em = (const float*)d_in[3];
    const float* pj = (const float*)d_in[4];
    const float* rw = (const float*)d_in[5];
    float* out = (float*)d_out;

    dim3 grid(512);   // (b: 8) x (d-tiles: 64)
    dim3 block(128);  // 2 waves: 16 cols x 8 mode-groups
    mega_kernel<<<grid, block, 0, stream>>>(x, df, cf, em, pj, rw, out);
}

// Round 5
// 160.660 us; speedup vs baseline: 3.0312x; 1.9191x over previous
//
#include <hip/hip_runtime.h>

// MegalodonEMA single-pass: 64-mode recurrence, coalesced via LDS transpose.
// Block = (b, 16 consecutive d), 128 threads = 2 waves.
// Lane role: col = wv*8 + (lane>>3)  (16 cols/block), q = lane&7 = mode-group.
// Each lane: 8 modes n = q*8+i. Per timestep: 16 FMA + 3 DPP-adds (VALU pipe,
// NOT ds_swizzle -- R4's __shfl_xor was LDS-pipe latency-bound at 1 wave/SIMD).
// Deferred silu: lane keeps v for timesteps t%8==q, silu once per 8 steps.
// x staged per 64-step chunk into LDS (float4, reg double-buffered);
// y staged in LDS tile, stored coalesced. 2 barriers per chunk.

#define LSEQ 2048
#define BSZ 8
#define DIM 1024
#define ND 64
#define CH 64
#define NCH 32
#define TD 16
#define BD 8192
#define YP 20   // ytile pitch: bank (20q + c)%32 -> worst 2-way (free)

// DPP controls: quad_perm[1,0,3,2]=0xB1 (xor1), quad_perm[2,3,0,1]=0x4E (xor2),
// row_half_mirror=0x141 (lane^7 within 8 -- crosses quads once quad-sums uniform).
template <int CTRL>
__device__ __forceinline__ float dpp_add(float v) {
    const int r = __builtin_amdgcn_update_dpp(0, __float_as_int(v), CTRL, 0xF, 0xF, true);
    return v + __int_as_float(r);
}

__global__ __launch_bounds__(128) void mega_kernel(
    const float* __restrict__ x,
    const float* __restrict__ dfp,
    const float* __restrict__ cfp,
    const float* __restrict__ emp,
    const float* __restrict__ pjp,
    const float* __restrict__ rwp,
    float* __restrict__ out)
{
    __shared__ float xb[2][CH * TD];  // 2 x 4KB
    __shared__ float yt[CH * YP];     // 5KB

    const int tid  = threadIdx.x;
    const int lane = tid & 63;
    const int wv   = tid >> 6;
    const int q    = lane & 7;        // mode-group
    const int csub = lane >> 3;       // 0..7
    const int col  = wv * 8 + csub;   // 0..15
    const int blk  = blockIdx.x;
    const int b    = blk >> 6;        // 0..7
    const int d0   = (blk & 63) * TD;
    const int d    = d0 + col;

    // ---- per-lane mode params: n = q*8 + i ----
    float w[8], cc[8];
    {
        const int pb = d * ND + q * 8;
        const float4 df0 = *(const float4*)(dfp + pb);
        const float4 df1 = *(const float4*)(dfp + pb + 4);
        const float4 cf0 = *(const float4*)(cfp + pb);
        const float4 cf1 = *(const float4*)(cfp + pb + 4);
        const float4 em0 = *(const float4*)(emp + pb);
        const float4 em1 = *(const float4*)(emp + pb + 4);
        const float4 pj0 = *(const float4*)(pjp + pb);
        const float4 pj1 = *(const float4*)(pjp + pb + 4);
        const float dfv[8] = {df0.x, df0.y, df0.z, df0.w, df1.x, df1.y, df1.z, df1.w};
        const float cfv[8] = {cf0.x, cf0.y, cf0.z, cf0.w, cf1.x, cf1.y, cf1.z, cf1.w};
        const float emv[8] = {em0.x, em0.y, em0.z, em0.w, em1.x, em1.y, em1.z, em1.w};
        const float pjv[8] = {pj0.x, pj0.y, pj0.z, pj0.w, pj1.x, pj1.y, pj1.z, pj1.w};
        #pragma unroll
        for (int i = 0; i < 8; ++i) {
            const float sd = 1.0f / (1.0f + __expf(-dfv[i]));
            const float sc = 1.0f / (1.0f + __expf(-cfv[i]));
            w[i]  = 1.0f - sd * sc;
            cc[i] = sd * emv[i] * pjv[i] * 0.125f;  // 1/sqrt(64)
        }
    }
    const float rwd = rwp[d];

    const float* xg = x   + (size_t)b * DIM + d0;
    float*       og = out + (size_t)b * DIM + d0;

    // staging map: f in {tid, tid+128}: row r=f>>2, col4 c4=(f&3)*4
    const int r0 = tid >> 2;
    const int c4 = (tid & 3) * 4;

    float4 nx0 = *(const float4*)(xg + (size_t)r0 * BD + c4);
    float4 nx1 = *(const float4*)(xg + (size_t)(r0 + 32) * BD + c4);

    float h[8];
    #pragma unroll
    for (int i = 0; i < 8; ++i) h[i] = 0.0f;

    for (int g = 0; g < NCH; ++g) {
        float* xbuf = xb[g & 1];
        *(float4*)(xbuf + r0 * TD + c4) = nx0;
        *(float4*)(xbuf + (r0 + 32) * TD + c4) = nx1;
        if (g + 1 < NCH) {  // prefetch next chunk (consumed next iter)
            nx0 = *(const float4*)(xg + (size_t)((g + 1) * CH + r0) * BD + c4);
            nx1 = *(const float4*)(xg + (size_t)((g + 1) * CH + r0 + 32) * BD + c4);
        }
        __syncthreads();  // x tile ready

        #pragma unroll 2
        for (int t8 = 0; t8 < 8; ++t8) {
            float vsave = 0.0f;
            #pragma unroll
            for (int k = 0; k < 8; ++k) {
                const float xv = xbuf[(t8 * 8 + k) * TD + col];  // 8-lane bcast
                float a0 = 0.0f, a1 = 0.0f;  // split acc chain: 4-deep each
                #pragma unroll
                for (int i = 0; i < 4; ++i) {
                    h[i] = fmaf(w[i], h[i], xv);
                    a0 = fmaf(cc[i], h[i], a0);
                }
                #pragma unroll
                for (int i = 4; i < 8; ++i) {
                    h[i] = fmaf(w[i], h[i], xv);
                    a1 = fmaf(cc[i], h[i], a1);
                }
                float acc = a0 + a1;
                acc = dpp_add<0xB1>(acc);    // + lane^1 (quad_perm 1,0,3,2)
                acc = dpp_add<0x4E>(acc);    // + lane^2 (quad_perm 2,3,0,1)
                acc = dpp_add<0x141>(acc);   // + lane^7 (row_half_mirror)
                const float v = fmaf(rwd, xv, acc);
                if (q == k) vsave = v;       // compile-time k: cmp+cndmask
            }
            const float sv = vsave / (1.0f + __expf(-vsave));  // silu, 1/8 rate
            yt[(t8 * 8 + q) * YP + col] = sv;
        }
        __syncthreads();  // y tile complete (also: xbuf reads done)

        const float4 o0 = *(const float4*)(yt + r0 * YP + c4);
        const float4 o1 = *(const float4*)(yt + (r0 + 32) * YP + c4);
        *(float4*)(og + (size_t)(g * CH + r0) * BD + c4) = o0;
        *(float4*)(og + (size_t)(g * CH + r0 + 32) * BD + c4) = o1;
        // no third barrier: next yt write is after next __syncthreads,
        // which orders these ds_reads; next ds_write targets xb[(g+1)&1],
        // whose readers finished two barriers ago.
    }
}

extern "C" void kernel_launch(void* const* d_in, const int* in_sizes, int n_in,
                              void* d_out, int out_size, void* d_ws, size_t ws_size,
                              hipStream_t stream) {
    const float* x  = (const float*)d_in[0];
    const float* df = (const float*)d_in[1];
    const float* cf = (const float*)d_in[2];
    const float* em = (const float*)d_in[3];
    const float* pj = (const float*)d_in[4];
    const float* rw = (const float*)d_in[5];
    float* out = (float*)d_out;

    dim3 grid(512);   // (b: 8) x (d-tiles: 64)
    dim3 block(128);  // 2 waves: 16 cols x 8 mode-groups
    mega_kernel<<<grid, block, 0, stream>>>(x, df, cf, em, pj, rw, out);
}

// Round 6
// 116.580 us; speedup vs baseline: 4.1773x; 1.3781x over previous
//
#include <hip/hip_runtime.h>

// MegalodonEMA, 2-pass chunked state-space to break the 1-wave/SIMD latency wall.
// Segment L=2048 into SEGS=4 x 512. Pass1: per (b,d-tile,seg) block, compute
// per-mode Horner sums S[n] = sum_m w^{511-m} x[m] over the segment (register
// scan, 8 modes/lane). Pass2: h0 from S via w^512-weighted Horner (9 squarings),
// then the full 64-mode recurrence + reduction + silu on 512 steps.
// Parallelism: 2048 blocks (4 waves/SIMD) vs single-pass 512 (1/SIMD).
// x tile staged TRANSPOSED [col][t] pitch 68: b128 reads are 8-lane broadcasts
// (conflict-free), 24 DS ops/chunk vs 66.

#define BSZ 8
#define DIM 1024
#define ND 64
#define CH 64
#define BD 8192
#define SEGS 4
#define SEGLEN 512
#define CPS 8          // chunks per segment
#define TD 16          // d-columns per block
#define XP 68          // x-tile pitch (words): 4-aligned (b128 ok), banks 4*col
#define YP 20          // y-tile pitch: worst 2-way (free)

// DPP: quad_perm[1,0,3,2]=0xB1 (xor1), quad_perm[2,3,0,1]=0x4E (xor2),
// row_half_mirror=0x141 (lane^7 within 8; valid once quad-sums uniform).
template <int CTRL>
__device__ __forceinline__ float dpp_add(float v) {
    const int r = __builtin_amdgcn_update_dpp(0, __float_as_int(v), CTRL, 0xF, 0xF, true);
    return v + __int_as_float(r);
}

__device__ __forceinline__ void load_modes_w(const float* dfp, const float* cfp,
                                             int d, int q, float* w) {
    const int pb = d * ND + q * 8;
    const float4 df0 = *(const float4*)(dfp + pb);
    const float4 df1 = *(const float4*)(dfp + pb + 4);
    const float4 cf0 = *(const float4*)(cfp + pb);
    const float4 cf1 = *(const float4*)(cfp + pb + 4);
    const float dfv[8] = {df0.x, df0.y, df0.z, df0.w, df1.x, df1.y, df1.z, df1.w};
    const float cfv[8] = {cf0.x, cf0.y, cf0.z, cf0.w, cf1.x, cf1.y, cf1.z, cf1.w};
    #pragma unroll
    for (int i = 0; i < 8; ++i) {
        const float sd = 1.0f / (1.0f + __expf(-dfv[i]));
        const float sc = 1.0f / (1.0f + __expf(-cfv[i]));
        w[i] = 1.0f - sd * sc;
    }
}

// ---------------- pass 1: segment Horner sums ----------------
__global__ __launch_bounds__(128, 4) void mega_pass1(
    const float* __restrict__ x,
    const float* __restrict__ dfp,
    const float* __restrict__ cfp,
    float* __restrict__ S)
{
    __shared__ float xb[2][TD * XP];

    const int tid = threadIdx.x;
    const int lane = tid & 63;
    const int wv = tid >> 6;
    const int q = lane & 7;
    const int col = wv * 8 + (lane >> 3);
    const int blk = blockIdx.x;
    const int dt  = blk & 63;
    const int b   = (blk >> 6) & 7;
    const int seg = blk >> 9;
    const int d   = dt * TD + col;

    float w[8];
    load_modes_w(dfp, cfp, d, q, w);

    const int r0 = tid >> 2;
    const int c4 = (tid & 3) * 4;
    const float* xg = x + (size_t)(seg * SEGLEN) * BD + b * DIM + dt * TD;

    float4 nx0 = *(const float4*)(xg + (size_t)r0 * BD + c4);
    float4 nx1 = *(const float4*)(xg + (size_t)(r0 + 32) * BD + c4);

    float h[8];
    #pragma unroll
    for (int i = 0; i < 8; ++i) h[i] = 0.0f;

    for (int g = 0; g < CPS; ++g) {
        float* xbuf = xb[g & 1];
        const float nv0[4] = {nx0.x, nx0.y, nx0.z, nx0.w};
        const float nv1[4] = {nx1.x, nx1.y, nx1.z, nx1.w};
        #pragma unroll
        for (int e = 0; e < 4; ++e) {
            xbuf[(c4 + e) * XP + r0]      = nv0[e];
            xbuf[(c4 + e) * XP + r0 + 32] = nv1[e];
        }
        if (g + 1 < CPS) {
            nx0 = *(const float4*)(xg + (size_t)((g + 1) * CH + r0) * BD + c4);
            nx1 = *(const float4*)(xg + (size_t)((g + 1) * CH + r0 + 32) * BD + c4);
        }
        __syncthreads();  // single barrier/chunk: double buffer makes it safe

        const float* xcol = xbuf + col * XP;
        #pragma unroll 2
        for (int t8 = 0; t8 < 8; ++t8) {
            const float4 tva = *(const float4*)(xcol + t8 * 8);
            const float4 tvb = *(const float4*)(xcol + t8 * 8 + 4);
            const float tvs[8] = {tva.x, tva.y, tva.z, tva.w,
                                  tvb.x, tvb.y, tvb.z, tvb.w};
            #pragma unroll
            for (int k = 0; k < 8; ++k) {
                const float xv = tvs[k];
                #pragma unroll
                for (int i = 0; i < 8; ++i) h[i] = fmaf(w[i], h[i], xv);
            }
        }
    }

    const size_t sb = ((size_t)(seg * BSZ + b) * 64 + dt) * 1024 + col * 64 + q * 8;
    *(float4*)(S + sb)     = make_float4(h[0], h[1], h[2], h[3]);
    *(float4*)(S + sb + 4) = make_float4(h[4], h[5], h[6], h[7]);
}

// ---------------- pass 2: full recurrence per segment ----------------
__global__ __launch_bounds__(128, 4) void mega_pass2(
    const float* __restrict__ x,
    const float* __restrict__ dfp,
    const float* __restrict__ cfp,
    const float* __restrict__ emp,
    const float* __restrict__ pjp,
    const float* __restrict__ rwp,
    const float* __restrict__ S,
    float* __restrict__ out)
{
    __shared__ float xb[2][TD * XP];
    __shared__ float yt[CH * YP];

    const int tid = threadIdx.x;
    const int lane = tid & 63;
    const int wv = tid >> 6;
    const int q = lane & 7;
    const int col = wv * 8 + (lane >> 3);
    const int blk = blockIdx.x;
    const int dt  = blk & 63;
    const int b   = (blk >> 6) & 7;
    const int seg = blk >> 9;
    const int d   = dt * TD + col;

    // full mode params
    float w[8], cc[8];
    {
        const int pb = d * ND + q * 8;
        const float4 df0 = *(const float4*)(dfp + pb);
        const float4 df1 = *(const float4*)(dfp + pb + 4);
        const float4 cf0 = *(const float4*)(cfp + pb);
        const float4 cf1 = *(const float4*)(cfp + pb + 4);
        const float4 em0 = *(const float4*)(emp + pb);
        const float4 em1 = *(const float4*)(emp + pb + 4);
        const float4 pj0 = *(const float4*)(pjp + pb);
        const float4 pj1 = *(const float4*)(pjp + pb + 4);
        const float dfv[8] = {df0.x, df0.y, df0.z, df0.w, df1.x, df1.y, df1.z, df1.w};
        const float cfv[8] = {cf0.x, cf0.y, cf0.z, cf0.w, cf1.x, cf1.y, cf1.z, cf1.w};
        const float emv[8] = {em0.x, em0.y, em0.z, em0.w, em1.x, em1.y, em1.z, em1.w};
        const float pjv[8] = {pj0.x, pj0.y, pj0.z, pj0.w, pj1.x, pj1.y, pj1.z, pj1.w};
        #pragma unroll
        for (int i = 0; i < 8; ++i) {
            const float sd = 1.0f / (1.0f + __expf(-dfv[i]));
            const float sc = 1.0f / (1.0f + __expf(-cfv[i]));
            w[i]  = 1.0f - sd * sc;
            cc[i] = sd * emv[i] * pjv[i] * 0.125f;
        }
    }
    const float rwd = rwp[d];

    // entry state h0 = sum_{s'<seg} (w^512)^{seg-1-s'} S_{s'}  (Horner)
    float h[8];
    #pragma unroll
    for (int i = 0; i < 8; ++i) h[i] = 0.0f;
    if (seg > 0) {
        float w512[8];
        #pragma unroll
        for (int i = 0; i < 8; ++i) {
            float s = w[i];
            #pragma unroll
            for (int r = 0; r < 9; ++r) s = s * s;  // w^(2^9) = w^512
            w512[i] = s;
        }
        for (int sp = 0; sp < seg; ++sp) {
            const size_t sb = ((size_t)(sp * BSZ + b) * 64 + dt) * 1024 + col * 64 + q * 8;
            const float4 a = *(const float4*)(S + sb);
            const float4 bb = *(const float4*)(S + sb + 4);
            const float sv[8] = {a.x, a.y, a.z, a.w, bb.x, bb.y, bb.z, bb.w};
            #pragma unroll
            for (int i = 0; i < 8; ++i) h[i] = fmaf(w512[i], h[i], sv[i]);
        }
    }

    const int r0 = tid >> 2;
    const int c4 = (tid & 3) * 4;
    const float* xg = x   + (size_t)(seg * SEGLEN) * BD + b * DIM + dt * TD;
    float*       og = out + (size_t)(seg * SEGLEN) * BD + b * DIM + dt * TD;

    float4 nx0 = *(const float4*)(xg + (size_t)r0 * BD + c4);
    float4 nx1 = *(const float4*)(xg + (size_t)(r0 + 32) * BD + c4);

    for (int g = 0; g < CPS; ++g) {
        float* xbuf = xb[g & 1];
        const float nv0[4] = {nx0.x, nx0.y, nx0.z, nx0.w};
        const float nv1[4] = {nx1.x, nx1.y, nx1.z, nx1.w};
        #pragma unroll
        for (int e = 0; e < 4; ++e) {
            xbuf[(c4 + e) * XP + r0]      = nv0[e];
            xbuf[(c4 + e) * XP + r0 + 32] = nv1[e];
        }
        if (g + 1 < CPS) {
            nx0 = *(const float4*)(xg + (size_t)((g + 1) * CH + r0) * BD + c4);
            nx1 = *(const float4*)(xg + (size_t)((g + 1) * CH + r0 + 32) * BD + c4);
        }
        __syncthreads();  // x tile ready

        const float* xcol = xbuf + col * XP;
        #pragma unroll 2
        for (int t8 = 0; t8 < 8; ++t8) {
            const float4 tva = *(const float4*)(xcol + t8 * 8);
            const float4 tvb = *(const float4*)(xcol + t8 * 8 + 4);
            const float tvs[8] = {tva.x, tva.y, tva.z, tva.w,
                                  tvb.x, tvb.y, tvb.z, tvb.w};
            float vsave = 0.0f;
            #pragma unroll
            for (int k = 0; k < 8; ++k) {
                const float xv = tvs[k];
                float a0 = 0.0f, a1 = 0.0f;
                #pragma unroll
                for (int i = 0; i < 4; ++i) {
                    h[i] = fmaf(w[i], h[i], xv);
                    a0 = fmaf(cc[i], h[i], a0);
                }
                #pragma unroll
                for (int i = 4; i < 8; ++i) {
                    h[i] = fmaf(w[i], h[i], xv);
                    a1 = fmaf(cc[i], h[i], a1);
                }
                float acc = a0 + a1;
                acc = dpp_add<0xB1>(acc);
                acc = dpp_add<0x4E>(acc);
                acc = dpp_add<0x141>(acc);
                const float v = fmaf(rwd, xv, acc);
                if (q == k) vsave = v;
            }
            yt[(t8 * 8 + q) * YP + col] = vsave / (1.0f + __expf(-vsave));
        }
        __syncthreads();  // y tile complete; xbuf reads done

        const float4 o0 = *(const float4*)(yt + r0 * YP + c4);
        const float4 o1 = *(const float4*)(yt + (r0 + 32) * YP + c4);
        *(float4*)(og + (size_t)(g * CH + r0) * BD + c4) = o0;
        *(float4*)(og + (size_t)(g * CH + r0 + 32) * BD + c4) = o1;
    }
}

extern "C" void kernel_launch(void* const* d_in, const int* in_sizes, int n_in,
                              void* d_out, int out_size, void* d_ws, size_t ws_size,
                              hipStream_t stream) {
    const float* x  = (const float*)d_in[0];
    const float* df = (const float*)d_in[1];
    const float* cf = (const float*)d_in[2];
    const float* em = (const float*)d_in[3];
    const float* pj = (const float*)d_in[4];
    const float* rw = (const float*)d_in[5];
    float* out = (float*)d_out;
    float* S   = (float*)d_ws;   // SEGS*BSZ*DIM*ND floats = 8 MB

    dim3 grid(SEGS * BSZ * 64);  // 2048 blocks: (seg, b, d-tile)
    dim3 block(128);
    mega_pass1<<<grid, block, 0, stream>>>(x, df, cf, S);
    mega_pass2<<<grid, block, 0, stream>>>(x, df, cf, em, pj, rw, S, out);
}

// Round 7
// 112.336 us; speedup vs baseline: 4.3351x; 1.0378x over previous
//
#include <hip/hip_runtime.h>

// MegalodonEMA, 2-pass chunked state-space. SEGS=8 x 256 for 8 waves/SIMD TLP.
// Pass1 (segs 0..6): per-mode Horner sums S[n] = sum_m w^{255-m} x[m], bf16 out.
// Pass2: entry state via w^256-Horner over S, then 64-mode recurrence.
// Reduction restructured: per-t8 8x8 TRANSPOSE-reduce in registers
// (8cnd+4dpp / 4dpp / 4dpp / 3cnd) instead of per-step 3-DPP butterfly --
// 23 VALU per 8 steps vs 56, and the serial DPP chain runs 1x per 8 steps.
// Lane mapping: q = lane bits {0,1,3} (xor1/xor2 = quad_perm, xor8 = row_ror:8),
// col = lane bits {2,4,5}.

#define BSZ 8
#define DIM 1024
#define ND 64
#define CH 64
#define BD 8192
#define SEGS 8
#define SEGLEN 256
#define CPS 4          // chunks of 64 per segment
#define TD 16
#define XP 68          // x-tile pitch (transposed [col][t])
#define YP 20

template <int CTRL>
__device__ __forceinline__ float dpp_mov(float v) {
    return __int_as_float(__builtin_amdgcn_update_dpp(0, __float_as_int(v), CTRL, 0xF, 0xF, true));
}

__device__ __forceinline__ uint32_t pk_bf16(float a, float b) {
    uint32_t ua = __float_as_uint(a); ua = (ua + 0x7FFFu + ((ua >> 16) & 1u)) >> 16;
    uint32_t ub = __float_as_uint(b); ub = (ub + 0x7FFFu + ((ub >> 16) & 1u)) >> 16;
    return ua | (ub << 16);
}

// ---------------- pass 1: segment Horner sums (segs 0..SEGS-2) ----------------
__global__ __launch_bounds__(128, 8) void mega_pass1(
    const float* __restrict__ x,
    const float* __restrict__ dfp,
    const float* __restrict__ cfp,
    ushort* __restrict__ S)
{
    __shared__ float xb[2][TD * XP];

    const int tid = threadIdx.x;
    const int lane = tid & 63;
    const int wv = tid >> 6;
    const int q   = (lane & 3) | (((lane >> 3) & 1) << 2);
    const int col = wv * 8 + ((lane >> 2) & 1) + ((lane >> 4) & 3) * 2;
    const int blk = blockIdx.x;
    const int dt  = blk & 63;
    const int b   = (blk >> 6) & 7;
    const int seg = blk >> 9;           // 0..6
    const int d   = dt * TD + col;

    float w[8];
    {
        const int pb = d * ND + q * 8;
        const float4 df0 = *(const float4*)(dfp + pb);
        const float4 df1 = *(const float4*)(dfp + pb + 4);
        const float4 cf0 = *(const float4*)(cfp + pb);
        const float4 cf1 = *(const float4*)(cfp + pb + 4);
        const float dfv[8] = {df0.x, df0.y, df0.z, df0.w, df1.x, df1.y, df1.z, df1.w};
        const float cfv[8] = {cf0.x, cf0.y, cf0.z, cf0.w, cf1.x, cf1.y, cf1.z, cf1.w};
        #pragma unroll
        for (int i = 0; i < 8; ++i) {
            const float sd = 1.0f / (1.0f + __expf(-dfv[i]));
            const float sc = 1.0f / (1.0f + __expf(-cfv[i]));
            w[i] = 1.0f - sd * sc;
        }
    }

    const int r0 = tid >> 2;
    const int c4 = (tid & 3) * 4;
    const float* xg = x + (size_t)(seg * SEGLEN) * BD + b * DIM + dt * TD;

    float4 nx0 = *(const float4*)(xg + (size_t)r0 * BD + c4);
    float4 nx1 = *(const float4*)(xg + (size_t)(r0 + 32) * BD + c4);

    float h[8];
    #pragma unroll
    for (int i = 0; i < 8; ++i) h[i] = 0.0f;

    for (int g = 0; g < CPS; ++g) {
        float* xbuf = xb[g & 1];
        const float nv0[4] = {nx0.x, nx0.y, nx0.z, nx0.w};
        const float nv1[4] = {nx1.x, nx1.y, nx1.z, nx1.w};
        #pragma unroll
        for (int e = 0; e < 4; ++e) {
            xbuf[(c4 + e) * XP + r0]      = nv0[e];
            xbuf[(c4 + e) * XP + r0 + 32] = nv1[e];
        }
        if (g + 1 < CPS) {
            nx0 = *(const float4*)(xg + (size_t)((g + 1) * CH + r0) * BD + c4);
            nx1 = *(const float4*)(xg + (size_t)((g + 1) * CH + r0 + 32) * BD + c4);
        }
        __syncthreads();

        const float* xcol = xbuf + col * XP;
        #pragma unroll 2
        for (int t8 = 0; t8 < 8; ++t8) {
            const float4 tva = *(const float4*)(xcol + t8 * 8);
            const float4 tvb = *(const float4*)(xcol + t8 * 8 + 4);
            const float tvs[8] = {tva.x, tva.y, tva.z, tva.w,
                                  tvb.x, tvb.y, tvb.z, tvb.w};
            #pragma unroll
            for (int k = 0; k < 8; ++k) {
                const float xv = tvs[k];
                #pragma unroll
                for (int i = 0; i < 8; ++i) h[i] = fmaf(w[i], h[i], xv);
            }
        }
    }

    const size_t sb = ((size_t)(seg * BSZ + b) * 64 + dt) * 1024 + col * 64 + q * 8;
    uint32_t pk[4] = {pk_bf16(h[0], h[1]), pk_bf16(h[2], h[3]),
                      pk_bf16(h[4], h[5]), pk_bf16(h[6], h[7])};
    *(uint4*)(S + sb) = make_uint4(pk[0], pk[1], pk[2], pk[3]);
}

// ---------------- pass 2: full recurrence per segment ----------------
__global__ __launch_bounds__(128, 8) void mega_pass2(
    const float* __restrict__ x,
    const float* __restrict__ dfp,
    const float* __restrict__ cfp,
    const float* __restrict__ emp,
    const float* __restrict__ pjp,
    const float* __restrict__ rwp,
    const ushort* __restrict__ S,
    float* __restrict__ out)
{
    __shared__ float xb[2][TD * XP];
    __shared__ float yt[CH * YP];

    const int tid = threadIdx.x;
    const int lane = tid & 63;
    const int wv = tid >> 6;
    const bool L0 = (lane & 1) != 0;
    const bool L1 = (lane & 2) != 0;
    const bool L3 = (lane & 8) != 0;
    const int q   = (lane & 3) | (((lane >> 3) & 1) << 2);
    const int col = wv * 8 + ((lane >> 2) & 1) + ((lane >> 4) & 3) * 2;
    const int blk = blockIdx.x;
    const int dt  = blk & 63;
    const int b   = (blk >> 6) & 7;
    const int seg = blk >> 9;          // 0..7
    const int d   = dt * TD + col;

    float w[8], cc[8];
    {
        const int pb = d * ND + q * 8;
        const float4 df0 = *(const float4*)(dfp + pb);
        const float4 df1 = *(const float4*)(dfp + pb + 4);
        const float4 cf0 = *(const float4*)(cfp + pb);
        const float4 cf1 = *(const float4*)(cfp + pb + 4);
        const float4 em0 = *(const float4*)(emp + pb);
        const float4 em1 = *(const float4*)(emp + pb + 4);
        const float4 pj0 = *(const float4*)(pjp + pb);
        const float4 pj1 = *(const float4*)(pjp + pb + 4);
        const float dfv[8] = {df0.x, df0.y, df0.z, df0.w, df1.x, df1.y, df1.z, df1.w};
        const float cfv[8] = {cf0.x, cf0.y, cf0.z, cf0.w, cf1.x, cf1.y, cf1.z, cf1.w};
        const float emv[8] = {em0.x, em0.y, em0.z, em0.w, em1.x, em1.y, em1.z, em1.w};
        const float pjv[8] = {pj0.x, pj0.y, pj0.z, pj0.w, pj1.x, pj1.y, pj1.z, pj1.w};
        #pragma unroll
        for (int i = 0; i < 8; ++i) {
            const float sd = 1.0f / (1.0f + __expf(-dfv[i]));
            const float sc = 1.0f / (1.0f + __expf(-cfv[i]));
            w[i]  = 1.0f - sd * sc;
            cc[i] = sd * emv[i] * pjv[i] * 0.125f;
        }
    }
    const float rwd = rwp[d];

    const int r0 = tid >> 2;
    const int c4 = (tid & 3) * 4;
    const float* xg = x   + (size_t)(seg * SEGLEN) * BD + b * DIM + dt * TD;
    float*       og = out + (size_t)(seg * SEGLEN) * BD + b * DIM + dt * TD;

    // issue first x loads before the entry-state Horner (overlap HBM latency)
    float4 nx0 = *(const float4*)(xg + (size_t)r0 * BD + c4);
    float4 nx1 = *(const float4*)(xg + (size_t)(r0 + 32) * BD + c4);

    // entry state h0 = sum_{sp<seg} (w^256)^{seg-1-sp} S_sp  (Horner)
    float h[8];
    #pragma unroll
    for (int i = 0; i < 8; ++i) h[i] = 0.0f;
    if (seg > 0) {
        float w256[8];
        #pragma unroll
        for (int i = 0; i < 8; ++i) {
            float s = w[i];
            #pragma unroll
            for (int r = 0; r < 8; ++r) s = s * s;  // w^(2^8) = w^256
            w256[i] = s;
        }
        for (int sp = 0; sp < seg; ++sp) {
            const size_t sb = ((size_t)(sp * BSZ + b) * 64 + dt) * 1024 + col * 64 + q * 8;
            const uint4 u = *(const uint4*)(S + sb);
            const uint32_t uv[4] = {u.x, u.y, u.z, u.w};
            #pragma unroll
            for (int j = 0; j < 4; ++j) {
                const float lo = __uint_as_float(uv[j] << 16);
                const float hi = __uint_as_float(uv[j] & 0xFFFF0000u);
                h[2*j]   = fmaf(w256[2*j],   h[2*j],   lo);
                h[2*j+1] = fmaf(w256[2*j+1], h[2*j+1], hi);
            }
        }
    }

    for (int g = 0; g < CPS; ++g) {
        float* xbuf = xb[g & 1];
        const float nv0[4] = {nx0.x, nx0.y, nx0.z, nx0.w};
        const float nv1[4] = {nx1.x, nx1.y, nx1.z, nx1.w};
        #pragma unroll
        for (int e = 0; e < 4; ++e) {
            xbuf[(c4 + e) * XP + r0]      = nv0[e];
            xbuf[(c4 + e) * XP + r0 + 32] = nv1[e];
        }
        if (g + 1 < CPS) {
            nx0 = *(const float4*)(xg + (size_t)((g + 1) * CH + r0) * BD + c4);
            nx1 = *(const float4*)(xg + (size_t)((g + 1) * CH + r0 + 32) * BD + c4);
        }
        __syncthreads();  // x tile ready

        const float* xcol = xbuf + col * XP;
        const float* xq   = xbuf + col * XP + q;   // residual read, imm offsets
        #pragma unroll 2
        for (int t8 = 0; t8 < 8; ++t8) {
            const float4 tva = *(const float4*)(xcol + t8 * 8);
            const float4 tvb = *(const float4*)(xcol + t8 * 8 + 4);
            const float tvs[8] = {tva.x, tva.y, tva.z, tva.w,
                                  tvb.x, tvb.y, tvb.z, tvb.w};
            float P[8];
            #pragma unroll
            for (int k = 0; k < 8; ++k) {
                const float xv = tvs[k];
                float a0 = 0.0f, a1 = 0.0f;
                #pragma unroll
                for (int i = 0; i < 4; ++i) {
                    h[i] = fmaf(w[i], h[i], xv);
                    a0 = fmaf(cc[i], h[i], a0);
                }
                #pragma unroll
                for (int i = 4; i < 8; ++i) {
                    h[i] = fmaf(w[i], h[i], xv);
                    a1 = fmaf(cc[i], h[i], a1);
                }
                P[k] = a0 + a1;
            }
            // 8x8 transpose-reduce across the q-group (lane bits 0,1,3):
            // r1: pair over bit0 (keep/give + xor1)
            float A[4];
            #pragma unroll
            for (int j = 0; j < 4; ++j) {
                const float keep = L0 ? P[2*j+1] : P[2*j];
                const float give = L0 ? P[2*j]   : P[2*j+1];
                A[j] = keep + dpp_mov<0xB1>(give);      // quad_perm(1,0,3,2)
            }
            // r2: bit1 (xor2) -- partners hold the same targets, same regs
            #pragma unroll
            for (int j = 0; j < 4; ++j) A[j] = A[j] + dpp_mov<0x4E>(A[j]);  // quad_perm(2,3,0,1)
            // r3: bit3 (xor8) via row_ror:8
            #pragma unroll
            for (int j = 0; j < 4; ++j) A[j] = A[j] + dpp_mov<0x128>(A[j]);
            // select target j* = (q>>1) = (L1, L3)
            const float s0v = L1 ? A[1] : A[0];
            const float s1v = L1 ? A[3] : A[2];
            const float R   = L3 ? s1v : s0v;

            const float xvq = xq[t8 * 8];            // ds_read, imm offset
            const float v = fmaf(rwd, xvq, R);
            yt[(t8 * 8 + q) * YP + col] = v / (1.0f + __expf(-v));
        }
        __syncthreads();  // y tile complete; xbuf reads done

        const float4 o0 = *(const float4*)(yt + r0 * YP + c4);
        const float4 o1 = *(const float4*)(yt + (r0 + 32) * YP + c4);
        *(float4*)(og + (size_t)(g * CH + r0) * BD + c4) = o0;
        *(float4*)(og + (size_t)(g * CH + r0 + 32) * BD + c4) = o1;
    }
}

extern "C" void kernel_launch(void* const* d_in, const int* in_sizes, int n_in,
                              void* d_out, int out_size, void* d_ws, size_t ws_size,
                              hipStream_t stream) {
    const float* x  = (const float*)d_in[0];
    const float* df = (const float*)d_in[1];
    const float* cf = (const float*)d_in[2];
    const float* em = (const float*)d_in[3];
    const float* pj = (const float*)d_in[4];
    const float* rw = (const float*)d_in[5];
    float* out = (float*)d_out;
    ushort* S  = (ushort*)d_ws;   // (SEGS-1)*BSZ*DIM*ND bf16 = 7.34 MB

    dim3 block(128);
    mega_pass1<<<dim3((SEGS - 1) * BSZ * 64), block, 0, stream>>>(x, df, cf, S);
    mega_pass2<<<dim3(SEGS * BSZ * 64), block, 0, stream>>>(x, df, cf, em, pj, rw, S, out);
}

// Round 8
// 92.903 us; speedup vs baseline: 5.2420x; 1.2092x over previous
//
#include <hip/hip_runtime.h>

// MegalodonEMA: 2-pass chunked state-space with MFMA inner chunks.
// Pass1 (VALU, proven): per (seg,b,dtile) Horner sums -> S (bf16), segs 0..2.
// Pass2 (MFMA): block = 16 waves = 16 consecutive d, one segment of 512.
//   Per chunk of 32 steps, per wave (one d):
//     U_g  = V @ x_g          (V[n][m] = w_n^{31-m}, 4 mfma)
//     y_g  = K @ x_g + T2 @ h (K[j][m]=kappa[j-m], T2[j][n]=c_n w_n^{j+1}, 6 mfma)
//     h   <- w32 * h + U_g    (16 VALU fma; the only sequential part)
//   Tables as bf16 A-fragments in VGPRs; x/y through LDS for coalescing.
// Frag layouts (guide-verified family): A/B: row|col = lane&15, k=(lane>>4)*8+e;
// C/D: col = lane&15, row = (lane>>4)*4 + reg.

#define BSZ 8
#define DIM 1024
#define ND 64
#define BD 8192
#define SEGS 4
#define SEGLEN 512
#define CH1 64        // pass1 chunk
#define CPS1 8        // pass1 chunks/seg
#define TD 16
#define XP1 68        // pass1 x-tile pitch
#define NCH2 16       // pass2 chunks/seg (32 steps each)

typedef short bf16x8 __attribute__((ext_vector_type(8)));
typedef float f32x4 __attribute__((ext_vector_type(4)));
union BF8 { uint32_t u[4]; bf16x8 v; };
#define MFMA __builtin_amdgcn_mfma_f32_16x16x32_bf16

__device__ __forceinline__ uint32_t pk_bf16(float a, float b) {
    uint32_t ua = __float_as_uint(a); ua = (ua + 0x7FFFu + ((ua >> 16) & 1u)) >> 16;
    uint32_t ub = __float_as_uint(b); ub = (ub + 0x7FFFu + ((ub >> 16) & 1u)) >> 16;
    return ua | (ub << 16);
}

// ---------------- pass 1: segment Horner sums (VALU; segs 0..2) ----------------
__global__ __launch_bounds__(128, 8) void mega_pass1(
    const float* __restrict__ x,
    const float* __restrict__ dfp,
    const float* __restrict__ cfp,
    ushort* __restrict__ S)
{
    __shared__ float xb[2][TD * XP1];

    const int tid = threadIdx.x;
    const int lane = tid & 63;
    const int wv = tid >> 6;
    const int q   = (lane & 3) | (((lane >> 3) & 1) << 2);
    const int col = wv * 8 + ((lane >> 2) & 1) + ((lane >> 4) & 3) * 2;
    const int blk = blockIdx.x;
    const int dt  = blk & 63;
    const int b   = (blk >> 6) & 7;
    const int seg = blk >> 9;           // 0..2
    const int d   = dt * TD + col;

    float w[8];
    {
        const int pb = d * ND + q * 8;
        const float4 df0 = *(const float4*)(dfp + pb);
        const float4 df1 = *(const float4*)(dfp + pb + 4);
        const float4 cf0 = *(const float4*)(cfp + pb);
        const float4 cf1 = *(const float4*)(cfp + pb + 4);
        const float dfv[8] = {df0.x, df0.y, df0.z, df0.w, df1.x, df1.y, df1.z, df1.w};
        const float cfv[8] = {cf0.x, cf0.y, cf0.z, cf0.w, cf1.x, cf1.y, cf1.z, cf1.w};
        #pragma unroll
        for (int i = 0; i < 8; ++i) {
            const float sd = 1.0f / (1.0f + __expf(-dfv[i]));
            const float sc = 1.0f / (1.0f + __expf(-cfv[i]));
            w[i] = 1.0f - sd * sc;
        }
    }

    const int r0 = tid >> 2;
    const int c4 = (tid & 3) * 4;
    const float* xg = x + (size_t)(seg * SEGLEN) * BD + b * DIM + dt * TD;

    float4 nx0 = *(const float4*)(xg + (size_t)r0 * BD + c4);
    float4 nx1 = *(const float4*)(xg + (size_t)(r0 + 32) * BD + c4);

    float h[8];
    #pragma unroll
    for (int i = 0; i < 8; ++i) h[i] = 0.0f;

    for (int g = 0; g < CPS1; ++g) {
        float* xbuf = xb[g & 1];
        const float nv0[4] = {nx0.x, nx0.y, nx0.z, nx0.w};
        const float nv1[4] = {nx1.x, nx1.y, nx1.z, nx1.w};
        #pragma unroll
        for (int e = 0; e < 4; ++e) {
            xbuf[(c4 + e) * XP1 + r0]      = nv0[e];
            xbuf[(c4 + e) * XP1 + r0 + 32] = nv1[e];
        }
        if (g + 1 < CPS1) {
            nx0 = *(const float4*)(xg + (size_t)((g + 1) * CH1 + r0) * BD + c4);
            nx1 = *(const float4*)(xg + (size_t)((g + 1) * CH1 + r0 + 32) * BD + c4);
        }
        __syncthreads();

        const float* xcol = xbuf + col * XP1;
        #pragma unroll 2
        for (int t8 = 0; t8 < 8; ++t8) {
            const float4 tva = *(const float4*)(xcol + t8 * 8);
            const float4 tvb = *(const float4*)(xcol + t8 * 8 + 4);
            const float tvs[8] = {tva.x, tva.y, tva.z, tva.w,
                                  tvb.x, tvb.y, tvb.z, tvb.w};
            #pragma unroll
            for (int k = 0; k < 8; ++k) {
                const float xv = tvs[k];
                #pragma unroll
                for (int i = 0; i < 8; ++i) h[i] = fmaf(w[i], h[i], xv);
            }
        }
    }

    const size_t sb = ((size_t)(seg * BSZ + b) * 64 + dt) * 1024 + col * 64 + q * 8;
    uint32_t pk[4] = {pk_bf16(h[0], h[1]), pk_bf16(h[2], h[3]),
                      pk_bf16(h[4], h[5]), pk_bf16(h[6], h[7])};
    *(uint4*)(S + sb) = make_uint4(pk[0], pk[1], pk[2], pk[3]);
}

// ---------------- pass 2: MFMA chunk loop ----------------
__global__ __launch_bounds__(1024) void mega_pass2(
    const float* __restrict__ x,
    const float* __restrict__ dfp,
    const float* __restrict__ cfp,
    const float* __restrict__ emp,
    const float* __restrict__ pjp,
    const float* __restrict__ rwp,
    const ushort* __restrict__ S,
    float* __restrict__ out)
{
    // LDS: x dbuf [16 d][8 b][36 l] (l XOR-swizzled by (d>>2)&3), y [256 rows][20],
    // hB per-wave [16 c][32 npair] u32 (npair XOR-swizzled), params, kappa.
    __shared__ __align__(16) float   xb[2][TD * 8 * 36];   // 36864 B
    __shared__ __align__(16) float   yt[256 * 20];         // 20480 B
    __shared__ __align__(16) uint32_t hbq[16 * 512];       // 32768 B
    __shared__ __align__(8)  float2  pclw[16 * 64];        // (c_n, log2 w_n) 8192 B
    __shared__ float pw[16 * 64];                          // w_n 4096 B
    __shared__ float kap[16 * 32];                         // kappa 2048 B

    const int tid = threadIdx.x;
    const int tl  = tid & 63;
    const int wv  = tid >> 6;          // wave = d-local (0..15)
    const int c   = tl & 15;
    const int g   = tl >> 4;           // 0..3
    const int blk = blockIdx.x;
    const int seg = blk >> 6;          // 0..3
    const int dt  = blk & 63;
    const int d0  = dt * TD;
    const int d   = d0 + wv;

    // ---- per-d mode params (lane = n) ----
    {
        const int pidx = d * ND + tl;
        const float sd = 1.0f / (1.0f + __expf(-dfp[pidx]));
        const float sc = 1.0f / (1.0f + __expf(-cfp[pidx]));
        const float wn = 1.0f - sd * sc;
        const float cn = sd * emp[pidx] * pjp[pidx] * 0.125f;
        pw[wv * 64 + tl] = wn;
        pclw[wv * 64 + tl] = make_float2(cn, log2f(wn));
    }
    const float rwd = rwp[d];

    // ---- stager mapping + first x prefetch (issued early) ----
    const int rid = tid >> 2;          // 0..255: l = rid>>3, b = rid&7
    const int l_s = rid >> 3;
    const int b_s = rid & 7;
    const int dq  = tid & 3;
    const float* xg_st = x + (size_t)(seg * SEGLEN + l_s) * BD + b_s * DIM + d0 + 4 * dq;
    float4 nx = *(const float4*)(xg_st);

    // ---- lane's C-layout mode set: n = 16T + 4g + r ----
    float lw16[16];
    #pragma unroll
    for (int T = 0; T < 4; ++T)
        #pragma unroll
        for (int r = 0; r < 4; ++r)
            lw16[T * 4 + r] = pclw[wv * 64 + 16 * T + 4 * g + r].y;

    // entry state h0 (C layout) from S via w512-Horner
    float h[16];
    #pragma unroll
    for (int i = 0; i < 16; ++i) h[i] = 0.0f;
    if (seg > 0) {
        float w512[16];
        #pragma unroll
        for (int i = 0; i < 16; ++i) w512[i] = exp2f(512.0f * lw16[i]);
        for (int sp = 0; sp < seg; ++sp) {
            const size_t sbase = ((size_t)(sp * BSZ + (c & 7)) * 64 + dt) * 1024 + wv * 64;
            #pragma unroll
            for (int T = 0; T < 4; ++T) {
                const uint2 u = *(const uint2*)(S + sbase + 16 * T + 4 * g);
                const float s0 = __uint_as_float(u.x << 16);
                const float s1 = __uint_as_float(u.x & 0xFFFF0000u);
                const float s2 = __uint_as_float(u.y << 16);
                const float s3 = __uint_as_float(u.y & 0xFFFF0000u);
                h[T*4+0] = fmaf(w512[T*4+0], h[T*4+0], s0);
                h[T*4+1] = fmaf(w512[T*4+1], h[T*4+1], s1);
                h[T*4+2] = fmaf(w512[T*4+2], h[T*4+2], s2);
                h[T*4+3] = fmaf(w512[T*4+3], h[T*4+3], s3);
            }
        }
    }
    float w32[16];
    #pragma unroll
    for (int i = 0; i < 16; ++i) w32[i] = exp2f(32.0f * lw16[i]);

    // ---- tables as A-fragments (bf16) ----
    BF8 Vf[4], T2f[2][2], Kf[2];
    #pragma unroll
    for (int T = 0; T < 4; ++T) {               // V[n][m] = w_n^{31-m}, n=16T+c, m=8g+e
        const float2 pcl = pclw[wv * 64 + 16 * T + c];
        const float winv = exp2f(-pcl.y);
        float ve = exp2f((float)(31 - 8 * g) * pcl.y);
        float vv[8];
        #pragma unroll
        for (int e = 0; e < 8; ++e) { vv[e] = ve; ve *= winv; }
        #pragma unroll
        for (int j = 0; j < 4; ++j) Vf[T].u[j] = pk_bf16(vv[2*j], vv[2*j+1]);
    }
    #pragma unroll
    for (int Tk = 0; Tk < 2; ++Tk) {            // T2[j][n] = c_n w_n^{j+1}, j=16Tj+c, n=32Tk+8g+e
        float2 m8[8];
        #pragma unroll
        for (int e = 0; e < 8; ++e) m8[e] = pclw[wv * 64 + 32 * Tk + 8 * g + e];
        #pragma unroll
        for (int Tj = 0; Tj < 2; ++Tj) {
            const float jf = (float)(16 * Tj + c + 1);
            float tv[8];
            #pragma unroll
            for (int e = 0; e < 8; ++e) tv[e] = m8[e].x * exp2f(jf * m8[e].y);
            #pragma unroll
            for (int j = 0; j < 4; ++j) T2f[Tj][Tk].u[j] = pk_bf16(tv[2*j], tv[2*j+1]);
        }
    }
    {   // kappa[p] = sum_n c_n w_n^p ; lane: p = tl>>1, half = tl&1
        const int p = tl >> 1, half = tl & 1;
        float acc = 0.0f;
        for (int i = 0; i < 32; ++i) {
            const float2 pc = pclw[wv * 64 + half * 32 + i];
            acc = fmaf(pc.x, exp2f((float)p * pc.y), acc);
        }
        const int prt = __builtin_amdgcn_update_dpp(0, __float_as_int(acc), 0xB1, 0xF, 0xF, true);
        acc += __int_as_float(prt);             // + lane^1
        if (!half) kap[wv * 32 + p] = acc;
    }
    #pragma unroll
    for (int Tj = 0; Tj < 2; ++Tj) {            // K[j][m] = kappa[j-m] (j>=m), j=16Tj+c, m=8g+e
        float kv[8];
        #pragma unroll
        for (int e = 0; e < 8; ++e) {
            const int pp = 16 * Tj + c - 8 * g - e;
            const float kr = kap[wv * 32 + (pp > 0 ? pp : 0)];
            kv[e] = (pp >= 0) ? kr : 0.0f;
        }
        #pragma unroll
        for (int j = 0; j < 4; ++j) Kf[Tj].u[j] = pk_bf16(kv[2*j], kv[2*j+1]);
    }

    // ---- chunk loop ----
    const int swl  = (wv >> 2) & 3;                        // x-tile l-XOR selector
    const int swzc = ((c & 3) << 3) | (((c >> 2) & 1) << 2); // hB npair-XOR
    uint32_t* hbw = hbq + wv * 512 + c * 32;
    float* ogbase = out + (size_t)(seg * SEGLEN) * BD + d0;
    const f32x4 zf = {0.0f, 0.0f, 0.0f, 0.0f};

    for (int ch = 0; ch < NCH2; ++ch) {
        // stage x chunk (all 1024 threads), prefetch next
        float* xbuf = xb[ch & 1];
        {
            const float nv[4] = {nx.x, nx.y, nx.z, nx.w};
            #pragma unroll
            for (int e = 0; e < 4; ++e)
                xbuf[((4 * dq + e) * 8 + b_s) * 36 + (l_s ^ (dq << 3))] = nv[e];
            if (ch + 1 < NCH2)
                nx = *(const float4*)(xg_st + (size_t)(ch + 1) * 32 * BD);
        }
        __syncthreads();   // x ready; prev y-store complete

        // xB fragment (k = 8g+e)
        const float* xrow = xbuf + (wv * 8 + (c & 7)) * 36;
        BF8 xB;
        {
            const int kb = (8 * g) ^ (swl << 3);
            const float4 fa = *(const float4*)(xrow + kb);
            const float4 fb = *(const float4*)(xrow + kb + 4);
            xB.u[0] = pk_bf16(fa.x, fa.y); xB.u[1] = pk_bf16(fa.z, fa.w);
            xB.u[2] = pk_bf16(fb.x, fb.y); xB.u[3] = pk_bf16(fb.z, fb.w);
        }
        // hB fragments via per-wave LDS transpose (C-layout -> B-layout)
        #pragma unroll
        for (int T = 0; T < 4; ++T) {
            const uint32_t u0 = pk_bf16(h[4*T+0], h[4*T+1]);
            const uint32_t u1 = pk_bf16(h[4*T+2], h[4*T+3]);
            *(uint2*)(&hbw[(8 * T + 2 * g) ^ swzc]) = make_uint2(u0, u1);
        }
        BF8 hB0, hB1;
        {
            const uint4 a = *(const uint4*)(&hbw[(4 * g) ^ swzc]);        // Tk=0
            const uint4 b2 = *(const uint4*)(&hbw[(16 + 4 * g) ^ swzc]);  // Tk=1
            hB0.u[0]=a.x; hB0.u[1]=a.y; hB0.u[2]=a.z; hB0.u[3]=a.w;
            hB1.u[0]=b2.x; hB1.u[1]=b2.y; hB1.u[2]=b2.z; hB1.u[3]=b2.w;
        }

        // y = K@x + T2@h  (carry uses chunk-START h)
        f32x4 y0 = MFMA(Kf[0].v, xB.v, zf, 0, 0, 0);
        f32x4 y1 = MFMA(Kf[1].v, xB.v, zf, 0, 0, 0);
        y0 = MFMA(T2f[0][0].v, hB0.v, y0, 0, 0, 0);
        y1 = MFMA(T2f[1][0].v, hB0.v, y1, 0, 0, 0);
        y0 = MFMA(T2f[0][1].v, hB1.v, y0, 0, 0, 0);
        y1 = MFMA(T2f[1][1].v, hB1.v, y1, 0, 0, 0);
        // U = V@x ; h <- w32*h + U
        #pragma unroll
        for (int T = 0; T < 4; ++T) {
            const f32x4 U = MFMA(Vf[T].v, xB.v, zf, 0, 0, 0);
            h[4*T+0] = fmaf(w32[4*T+0], h[4*T+0], U[0]);
            h[4*T+1] = fmaf(w32[4*T+1], h[4*T+1], U[1]);
            h[4*T+2] = fmaf(w32[4*T+2], h[4*T+2], U[2]);
            h[4*T+3] = fmaf(w32[4*T+3], h[4*T+3], U[3]);
        }

        // epilogue: residual + silu -> y tile (rows j*8+b, pitch 20)
        #pragma unroll
        for (int Tj = 0; Tj < 2; ++Tj) {
            const int jb = (16 * Tj + 4 * g) ^ (swl << 3);
            const float4 xres = *(const float4*)(xrow + jb);
            const float xr[4] = {xres.x, xres.y, xres.z, xres.w};
            const f32x4 yy = Tj ? y1 : y0;
            #pragma unroll
            for (int r = 0; r < 4; ++r) {
                const float v = yy[r] + rwd * xr[r];
                const float sv = v / (1.0f + __expf(-v));
                if (c < 8)
                    yt[((16 * Tj + 4 * g + r) * 8 + c) * 20 + wv] = sv;
            }
        }
        __syncthreads();   // y tile complete

        // coalesced store: thread -> (row rid, d-quad dq)
        const float4 ov = *(const float4*)(yt + rid * 20 + dq * 4);
        *(float4*)(ogbase + (size_t)(ch * 32 + l_s) * BD + b_s * DIM + 4 * dq) = ov;
    }
}

extern "C" void kernel_launch(void* const* d_in, const int* in_sizes, int n_in,
                              void* d_out, int out_size, void* d_ws, size_t ws_size,
                              hipStream_t stream) {
    const float* x  = (const float*)d_in[0];
    const float* df = (const float*)d_in[1];
    const float* cf = (const float*)d_in[2];
    const float* em = (const float*)d_in[3];
    const float* pj = (const float*)d_in[4];
    const float* rw = (const float*)d_in[5];
    float* out = (float*)d_out;
    ushort* S  = (ushort*)d_ws;   // 3*8*64*1024 bf16 = 3.1 MB

    mega_pass1<<<dim3((SEGS - 1) * BSZ * 64), dim3(128), 0, stream>>>(x, df, cf, S);
    mega_pass2<<<dim3(SEGS * 64), dim3(1024), 0, stream>>>(x, df, cf, em, pj, rw, S, out);
}